// Round 4
// baseline (477.875 us; speedup 1.0000x reference)
//
#include <hip/hip_runtime.h>
#include <math.h>

// Problem constants
// B=64, N=384, NFEAT=16, E=3, NHID=NOUT=128, ST_HID=64, ST_OUT=16
#define ROWS 24576            // B*N
#define ADJ_BE (384*384)      // per (b,e) adj matrix elems

typedef _Float16 h4v __attribute__((ext_vector_type(4)));
typedef _Float16 h8v __attribute__((ext_vector_type(8)));
typedef float f32x4 __attribute__((ext_vector_type(4)));

#define SPLIT_SCALE 2048.0f
#define INV_SPLIT_SCALE (1.0f / 2048.0f)

// ---------------- kernel 1a: h0 = x[b] @ emb^T, stored feature-major split-fp16 ----------------
__global__ __launch_bounds__(256) void k_h0split(const float* __restrict__ x,
        const float* __restrict__ emb_w, _Float16* __restrict__ Hh, _Float16* __restrict__ Hl) {
    __shared__ float embL[256];
    int t = threadIdx.x;
    if (t < 64) *(float4*)&embL[4 * t] = *(const float4*)(emb_w + 4 * t);
    __syncthreads();
    int gid = blockIdx.x * 256 + t;      // gid = b*384 + r
    int b = gid / 384, r = gid % 384;
    const float* xp = x + (size_t)gid * 16;
    float xr[16];
    *(float4*)&xr[0]  = *(const float4*)(xp);
    *(float4*)&xr[4]  = *(const float4*)(xp + 4);
    *(float4*)&xr[8]  = *(const float4*)(xp + 8);
    *(float4*)&xr[12] = *(const float4*)(xp + 12);
    size_t base = (size_t)b * 16 * 384 + r;
#pragma unroll
    for (int d = 0; d < 16; ++d) {
        float acc = 0.f;
#pragma unroll
        for (int k = 0; k < 16; ++k) acc = fmaf(xr[k], embL[d * 16 + k], acc);
        _Float16 h = (_Float16)acc;
        Hh[base + (size_t)d * 384] = h;
        Hl[base + (size_t)d * 384] = (_Float16)((acc - (float)h) * SPLIT_SCALE);
    }
}

// ---------------- kernel 1b: T[b,e] = adj[b,e] @ h0[b] via scaled-split fp16 MFMA ----------------
// 64-row tiles, grid (6 mt, 3 e, 64 b) = 1152 blocks. Reg-staged software pipeline.
__global__ __launch_bounds__(256) void k_adj16(const float* __restrict__ adj,
        const _Float16* __restrict__ Hh, const _Float16* __restrict__ Hl,
        float* __restrict__ T1) {
    int mt = blockIdx.x, e = blockIdx.y, b = blockIdx.z;
    const float* A = adj + (size_t)(b * 3 + e) * ADJ_BE + (size_t)mt * 64 * 384;
    const _Float16* BH = Hh + (size_t)b * 16 * 384;
    const _Float16* BL = Hl + (size_t)b * 16 * 384;

    __shared__ _Float16 Af[2][4][4][16][8];   // 8 KB (64 rows x 32 k, hi+lo)

    int t = threadIdx.x;
    int wave = t >> 6, lane = t & 63;
    int l16 = lane & 15, quad = lane >> 4;
    int r0s = t >> 3, q4s = t & 7;

    f32x4 acc0 = f32x4{0.f, 0.f, 0.f, 0.f};
    f32x4 acc1 = f32x4{0.f, 0.f, 0.f, 0.f};

    float4 ra[2];
    h8v rbh, rbl;
#pragma unroll
    for (int p = 0; p < 2; ++p)
        ra[p] = *(const float4*)(A + (size_t)(r0s + 32 * p) * 384 + 4 * q4s);
    rbh = *(const h8v*)(BH + (size_t)l16 * 384 + 8 * quad);
    rbl = *(const h8v*)(BL + (size_t)l16 * 384 + 8 * quad);

    for (int kc = 0; kc < 12; ++kc) {
#pragma unroll
        for (int p = 0; p < 2; ++p) {
            int r = r0s + 32 * p;
            float vv[4] = {ra[p].x, ra[p].y, ra[p].z, ra[p].w};
            h4v hh, ll;
#pragma unroll
            for (int c = 0; c < 4; ++c) {
                _Float16 h = (_Float16)vv[c];
                hh[c] = h;
                ll[c] = (_Float16)((vv[c] - (float)h) * SPLIT_SCALE);
            }
            *(h4v*)&Af[0][r >> 4][q4s >> 1][r & 15][(q4s & 1) * 4] = hh;
            *(h4v*)&Af[1][r >> 4][q4s >> 1][r & 15][(q4s & 1) * 4] = ll;
        }
        h8v b_h = rbh, b_l = rbl;
        __syncthreads();
        if (kc + 1 < 12) {
            int kn = (kc + 1) * 32;
#pragma unroll
            for (int p = 0; p < 2; ++p)
                ra[p] = *(const float4*)(A + (size_t)(r0s + 32 * p) * 384 + kn + 4 * q4s);
            rbh = *(const h8v*)(BH + (size_t)l16 * 384 + kn + 8 * quad);
            rbl = *(const h8v*)(BL + (size_t)l16 * 384 + kn + 8 * quad);
        }
        h8v a_h = *(const h8v*)&Af[0][wave][quad][l16][0];
        h8v a_l = *(const h8v*)&Af[1][wave][quad][l16][0];
        acc0 = __builtin_amdgcn_mfma_f32_16x16x32_f16(a_h, b_h, acc0, 0, 0, 0);
        acc1 = __builtin_amdgcn_mfma_f32_16x16x32_f16(a_h, b_l, acc1, 0, 0, 0);
        acc1 = __builtin_amdgcn_mfma_f32_16x16x32_f16(a_l, b_h, acc1, 0, 0, 0);
        __syncthreads();
    }
    float* Tp = T1 + ((size_t)(b * 3 + e) * 384 + (size_t)mt * 64 + wave * 16) * 16;
#pragma unroll
    for (int reg = 0; reg < 4; ++reg) {
        float v = fmaf(acc1[reg], INV_SPLIT_SCALE, acc0[reg]);
        Tp[(quad * 4 + reg) * 16 + l16] = v;
    }
}

// ---------------- kernel 2: h1 = sum_e relu(T[b,e] @ W1[e])  (K=16) ----------------
__global__ __launch_bounds__(256) void k_l1s2(const float* __restrict__ T1,
        const float* __restrict__ W1, float* __restrict__ h1) {
    __shared__ float wL[3][16][128];
    __shared__ float tL[3][64][17];
    int t = threadIdx.x;
    int rt = blockIdx.x;             // 64-row tile of flattened (b*384+m)
    int b = rt / 6, m0 = (rt % 6) * 64;
#pragma unroll
    for (int p = 0; p < 6; ++p) {    // W1: 3*16*128 floats = 1536 f4
        int idx = t + p * 256;
        float4 v = *(const float4*)(W1 + (size_t)idx * 4);
        int e = idx / 512, rem = idx % 512;
        int d = rem >> 5, q = rem & 31;
        *(float4*)&wL[e][d][q * 4] = v;
    }
#pragma unroll
    for (int p = 0; p < 3; ++p) {    // T tiles: 3*64*16 = 768 f4
        int idx = t + p * 256;
        int e = idx >> 8, rem = idx & 255;
        int r = rem >> 2, q = rem & 3;
        float4 v = *(const float4*)(T1 + ((size_t)(b * 3 + e) * 384 + m0 + r) * 16 + q * 4);
        tL[e][r][q*4+0] = v.x; tL[e][r][q*4+1] = v.y; tL[e][r][q*4+2] = v.z; tL[e][r][q*4+3] = v.w;
    }
    __syncthreads();
    int tx = t & 31;                 // cols c = tx + 32j, j<4
    int ty = t >> 5;                 // rows r = ty + 8i, i<8
    float tot[8][4] = {};
#pragma unroll
    for (int e = 0; e < 3; ++e) {
        float acc[8][4] = {};
#pragma unroll
        for (int d = 0; d < 16; ++d) {
            float a[8], w[4];
#pragma unroll
            for (int i = 0; i < 8; ++i) a[i] = tL[e][ty + 8 * i][d];
#pragma unroll
            for (int j = 0; j < 4; ++j) w[j] = wL[e][d][tx + 32 * j];
#pragma unroll
            for (int i = 0; i < 8; ++i)
#pragma unroll
                for (int j = 0; j < 4; ++j)
                    acc[i][j] = fmaf(a[i], w[j], acc[i][j]);
        }
#pragma unroll
        for (int i = 0; i < 8; ++i)
#pragma unroll
            for (int j = 0; j < 4; ++j)
                tot[i][j] += fmaxf(acc[i][j], 0.f);
    }
    float* out = h1 + (size_t)rt * 64 * 128;
#pragma unroll
    for (int i = 0; i < 8; ++i)
#pragma unroll
        for (int j = 0; j < 4; ++j)
            out[(ty + 8 * i) * 128 + tx + 32 * j] = tot[i][j];
}

// ---------------- kernel 3: S_t hi/lo fp16 = (h[b] @ W[e])^T  (64x128 tile, K=128) ----------------
__global__ __launch_bounds__(256) void k_support(const float* __restrict__ hin,
        const float* __restrict__ W, _Float16* __restrict__ Sh, _Float16* __restrict__ Sl) {
    int rt = blockIdx.x, e = blockIdx.y;
    int b = rt / 6, n0 = (rt % 6) * 64;   // n0 = node-index tile base (the k of the adj-gemm)
    const float* Hp = hin + (size_t)rt * 64 * 128;
    const float* Wp = W + (size_t)e * 128 * 128;
    __shared__ float aT[32][68];    // [k][row]
    __shared__ float bT[32][132];   // [k][col]
    int t = threadIdx.x;
    int tx = t & 15;                // cols {4tx..4tx+3, 64+4tx..}
    int ty = t >> 4;                // rows 4ty..4ty+3
    float acc[4][8] = {};
    for (int k0 = 0; k0 < 128; k0 += 32) {
        __syncthreads();
#pragma unroll
        for (int p = 0; p < 2; ++p) {          // h tile 64x32 transposed (512 f4)
            int idx = t + p * 256;
            int r = idx >> 3, q = idx & 7;
            float4 v = *(const float4*)(Hp + (size_t)r * 128 + k0 + q * 4);
            aT[q*4+0][r] = v.x; aT[q*4+1][r] = v.y; aT[q*4+2][r] = v.z; aT[q*4+3][r] = v.w;
        }
#pragma unroll
        for (int p = 0; p < 4; ++p) {          // W tile 32x128 (1024 f4)
            int idx = t + p * 256;
            int r = idx >> 5, q = idx & 31;
            *(float4*)&bT[r][q * 4] = *(const float4*)(Wp + (size_t)(k0 + r) * 128 + q * 4);
        }
        __syncthreads();
#pragma unroll
        for (int k = 0; k < 32; ++k) {
            float4 av = *(const float4*)&aT[k][4 * ty];
            float4 b0 = *(const float4*)&bT[k][4 * tx];
            float4 b1 = *(const float4*)&bT[k][64 + 4 * tx];
            float a[4] = {av.x, av.y, av.z, av.w};
            float bb[8] = {b0.x, b0.y, b0.z, b0.w, b1.x, b1.y, b1.z, b1.w};
#pragma unroll
            for (int i = 0; i < 4; ++i)
#pragma unroll
                for (int j = 0; j < 8; ++j)
                    acc[i][j] = fmaf(a[i], bb[j], acc[i][j]);
        }
    }
    size_t base = (size_t)(b * 3 + e) * 128 * 384;
#pragma unroll
    for (int j = 0; j < 8; ++j) {
        int n = (j < 4) ? (4 * tx + j) : (64 + 4 * tx + j - 4);
        h4v hh, ll;
#pragma unroll
        for (int i = 0; i < 4; ++i) {
            float v = acc[i][j];
            _Float16 h = (_Float16)v;
            hh[i] = h;
            ll[i] = (_Float16)((v - (float)h) * SPLIT_SCALE);
        }
        size_t off = base + (size_t)n * 384 + n0 + 4 * ty;
        *(h4v*)(Sh + off) = hh;
        *(h4v*)(Sl + off) = ll;
    }
}

// ---------------- kernel 4: out[b] += relu?(adj[b,e] @ S[b,e]) via scaled-split fp16 MFMA ----------------
// 96x128 block tile, XCD-swizzled 1D grid of 768 (see R2 comment). This revision:
//  - B fragments load DIRECTLY from global (L2/L3-resident S panels) — no B LDS staging.
//  - A-only LDS, double-buffered, ONE barrier per chunk (write Af[cur^1] while reading Af[cur]).
//  - l16 dim padded 16->17: staging-write bank conflicts 4-way -> <=2-way (free).
//  - Prefetch: A regs 2 chunks ahead, B regs 1 chunk ahead.
// acc0 = ah*Sh; acc1 = ah*Sl' + al'*Sh (scale 2^11); result = acc0 + acc1/2048.
template <int RELU>
__global__ __launch_bounds__(256, 3) void k_adj_mfma(const float* __restrict__ adj,
        const _Float16* __restrict__ Sh, const _Float16* __restrict__ Sl,
        float* __restrict__ out) {
    int bid = blockIdx.x;
    int xcd = bid & 7, l = bid >> 3;
    int pair = xcd * 24 + (l >> 2);           // 0..191 == b*3+e  (bijective)
    int mt = l & 3;
    int b = pair / 3;
    const float* A = adj + (size_t)pair * ADJ_BE + (size_t)mt * 96 * 384;
    const _Float16* Bh = Sh + (size_t)pair * 128 * 384;
    const _Float16* Bl = Sl + (size_t)pair * 128 * 384;
    float* O = out + ((size_t)b * 384 + mt * 96) * 128;

    // A-only double-buffered fragment-linear LDS, padded lane dim:
    // [dbuf][plane][subtile(16 rows)][quad(k8)][l16 pad 17][8 halves] = 25.5 KB
    __shared__ _Float16 Af[2][2][6][4][17][8];

    int t = threadIdx.x;
    int wave = t >> 6, lane = t & 63;
    int l16 = lane & 15, quad = lane >> 4;
    int wm = wave >> 1, wn = wave & 1;        // wave tile: rows 48*wm.., cols 64*wn..
    int r0s = t >> 3, q4s = t & 7;            // A staging: row (p adds 32), 4-float k-group

    f32x4 acc0[3][4], acc1[3][4];
#pragma unroll
    for (int i = 0; i < 3; ++i)
#pragma unroll
        for (int j = 0; j < 4; ++j) {
            acc0[i][j] = f32x4{0.f, 0.f, 0.f, 0.f};
            acc1[i][j] = f32x4{0.f, 0.f, 0.f, 0.f};
        }

    // B fragment offsets (per lane): col n = 16*(4*wn+j)+l16, k-offset 8*quad.
    // quads of one l16 cover contiguous 64 B -> full-cacheline requests.
    int boff[4];
#pragma unroll
    for (int j = 0; j < 4; ++j)
        boff[j] = (16 * (4 * wn + j) + l16) * 384 + 8 * quad;

    float4 ra[3];                             // A prefetch: 96x32 f32 = 768 f4, 3/thread
    h8v rbh[4], rbl[4];                       // B fragments for current chunk

    // prologue: chunk 0 A+B loads, stage A chunk 0 into Af[0], prefetch A chunk 1
#pragma unroll
    for (int p = 0; p < 3; ++p)
        ra[p] = *(const float4*)(A + (size_t)(r0s + 32 * p) * 384 + 4 * q4s);
#pragma unroll
    for (int j = 0; j < 4; ++j) {
        rbh[j] = *(const h8v*)(Bh + boff[j]);
        rbl[j] = *(const h8v*)(Bl + boff[j]);
    }
#pragma unroll
    for (int p = 0; p < 3; ++p) {
        int r = r0s + 32 * p;
        float vv[4] = {ra[p].x, ra[p].y, ra[p].z, ra[p].w};
        h4v hh, ll;
#pragma unroll
        for (int c = 0; c < 4; ++c) {
            _Float16 h = (_Float16)vv[c];
            hh[c] = h;
            ll[c] = (_Float16)((vv[c] - (float)h) * SPLIT_SCALE);
        }
        *(h4v*)&Af[0][0][r >> 4][q4s >> 1][r & 15][(q4s & 1) * 4] = hh;
        *(h4v*)&Af[0][1][r >> 4][q4s >> 1][r & 15][(q4s & 1) * 4] = ll;
    }
#pragma unroll
    for (int p = 0; p < 3; ++p)
        ra[p] = *(const float4*)(A + (size_t)(r0s + 32 * p) * 384 + 32 + 4 * q4s);
    __syncthreads();

    int cur = 0;
    for (int kc = 0; kc < 12; ++kc) {
        // fragments of current chunk from LDS
        h8v a_h[3], a_l[3];
#pragma unroll
        for (int i = 0; i < 3; ++i) {
            a_h[i] = *(const h8v*)&Af[cur][0][3 * wm + i][quad][l16][0];
            a_l[i] = *(const h8v*)&Af[cur][1][3 * wm + i][quad][l16][0];
        }
        // MFMA on current chunk (B straight from regs)
#pragma unroll
        for (int j = 0; j < 4; ++j)
#pragma unroll
            for (int i = 0; i < 3; ++i) {
                acc0[i][j] = __builtin_amdgcn_mfma_f32_16x16x32_f16(a_h[i], rbh[j], acc0[i][j], 0, 0, 0);
                acc1[i][j] = __builtin_amdgcn_mfma_f32_16x16x32_f16(a_h[i], rbl[j], acc1[i][j], 0, 0, 0);
                acc1[i][j] = __builtin_amdgcn_mfma_f32_16x16x32_f16(a_l[i], rbh[j], acc1[i][j], 0, 0, 0);
            }
        if (kc + 1 < 12) {
            int kn = (kc + 1) * 32;
            // B fragments for next chunk (consumed above; reload same regs)
#pragma unroll
            for (int j = 0; j < 4; ++j) {
                rbh[j] = *(const h8v*)(Bh + boff[j] + kn);
                rbl[j] = *(const h8v*)(Bl + boff[j] + kn);
            }
            // stage A chunk kc+1 into the other buffer (from ra, loaded 1-2 chunks ago)
#pragma unroll
            for (int p = 0; p < 3; ++p) {
                int r = r0s + 32 * p;
                float vv[4] = {ra[p].x, ra[p].y, ra[p].z, ra[p].w};
                h4v hh, ll;
#pragma unroll
                for (int c = 0; c < 4; ++c) {
                    _Float16 h = (_Float16)vv[c];
                    hh[c] = h;
                    ll[c] = (_Float16)((vv[c] - (float)h) * SPLIT_SCALE);
                }
                *(h4v*)&Af[cur ^ 1][0][r >> 4][q4s >> 1][r & 15][(q4s & 1) * 4] = hh;
                *(h4v*)&Af[cur ^ 1][1][r >> 4][q4s >> 1][r & 15][(q4s & 1) * 4] = ll;
            }
            if (kc + 2 < 12) {
                int kn2 = (kc + 2) * 32;
#pragma unroll
                for (int p = 0; p < 3; ++p)
                    ra[p] = *(const float4*)(A + (size_t)(r0s + 32 * p) * 384 + kn2 + 4 * q4s);
            }
        }
        __syncthreads();
        cur ^= 1;
    }
    // epilogue: C/D layout col=lane&15, row=quad*4+reg. Contiguous 16-lane atomics.
#pragma unroll
    for (int i = 0; i < 3; ++i) {
        int r0 = 48 * wm + 16 * i + quad * 4;
#pragma unroll
        for (int j = 0; j < 4; ++j) {
            int gc = 64 * wn + 16 * j + l16;
#pragma unroll
            for (int reg = 0; reg < 4; ++reg) {
                float v = fmaf(acc1[i][j][reg], INV_SPLIT_SCALE, acc0[i][j][reg]);
                if (RELU) v = fmaxf(v, 0.f);
                atomicAdd(O + (size_t)(r0 + reg) * 128 + gc, v);
            }
        }
    }
}

// ---------------- zero helper ----------------
__global__ void k_zero(float* __restrict__ p, int n4) {
    int i = blockIdx.x * blockDim.x + threadIdx.x;
    if (i < n4) ((float4*)p)[i] = float4{0.f, 0.f, 0.f, 0.f};
}

// ---------------- kernel 5: fused head ----------------
__global__ __launch_bounds__(256) void k_head(const float* __restrict__ h3,
        const float* __restrict__ st_w1, const float* __restrict__ st_b1,
        const float* __restrict__ st_w2, const float* __restrict__ st_b2,
        const float* __restrict__ rescale_w, float* __restrict__ out) {
    __shared__ float hL[64][132];
    __shared__ float w1L[64][132];
    __shared__ float ytL[64][68];
    __shared__ float w2L[32][68];
    __shared__ float b1L[64], b2L[32];
    int t = threadIdx.x;
    int r0 = blockIdx.x * 64;
#pragma unroll
    for (int p = 0; p < 8; ++p) {   // h rows 64x128 = 2048 f4
        int idx = t + p * 256;
        int r = idx >> 5, q = idx & 31;
        *(float4*)&hL[r][q * 4] = *(const float4*)(h3 + (size_t)(r0 + r) * 128 + q * 4);
    }
#pragma unroll
    for (int p = 0; p < 8; ++p) {   // w1 64x128
        int idx = t + p * 256;
        int r = idx >> 5, q = idx & 31;
        *(float4*)&w1L[r][q * 4] = *(const float4*)(st_w1 + (size_t)r * 128 + q * 4);
    }
#pragma unroll
    for (int p = 0; p < 2; ++p) {   // w2 32x64 = 512 f4
        int idx = t + p * 256;
        int r = idx >> 4, q = idx & 15;
        *(float4*)&w2L[r][q * 4] = *(const float4*)(st_w2 + (size_t)r * 64 + q * 4);
    }
    if (t < 64) b1L[t] = st_b1[t];
    else if (t < 96) b2L[t - 64] = st_b2[t - 64];
    __syncthreads();
    // phase 1: y = h @ w1^T + b1, tanh
    int tx = t & 15, ty = t >> 4;
    float acc[4][4] = {};
    for (int d = 0; d < 128; ++d) {
        float a[4], w[4];
#pragma unroll
        for (int i = 0; i < 4; ++i) a[i] = hL[ty + 16 * i][d];
#pragma unroll
        for (int j = 0; j < 4; ++j) w[j] = w1L[tx + 16 * j][d];
#pragma unroll
        for (int i = 0; i < 4; ++i)
#pragma unroll
            for (int j = 0; j < 4; ++j)
                acc[i][j] = fmaf(a[i], w[j], acc[i][j]);
    }
#pragma unroll
    for (int i = 0; i < 4; ++i)
#pragma unroll
        for (int j = 0; j < 4; ++j)
            ytL[ty + 16 * i][tx + 16 * j] = tanhf(acc[i][j] + b1L[tx + 16 * j]);
    __syncthreads();
    // phase 2: z = yt @ w2^T + b2; split into s (tanh*exp(rescale)) and t
    int tx8 = t & 7, ty32 = t >> 3;
    float acc2[2][4] = {};
    for (int d = 0; d < 64; ++d) {
        float a[2], w[4];
#pragma unroll
        for (int i = 0; i < 2; ++i) a[i] = ytL[ty32 + 32 * i][d];
#pragma unroll
        for (int j = 0; j < 4; ++j) w[j] = w2L[tx8 + 8 * j][d];
#pragma unroll
        for (int i = 0; i < 2; ++i)
#pragma unroll
            for (int j = 0; j < 4; ++j)
                acc2[i][j] = fmaf(a[i], w[j], acc2[i][j]);
    }
    float er = expf(rescale_w[0]);
#pragma unroll
    for (int i = 0; i < 2; ++i) {
        int r = r0 + ty32 + 32 * i;
#pragma unroll
        for (int j = 0; j < 4; ++j) {
            int c = tx8 + 8 * j;
            float z = acc2[i][j] + b2L[c];
            if (c < 16) out[(size_t)r * 16 + c] = er * tanhf(z);
            else        out[(size_t)(ROWS + r) * 16 + (c - 16)] = z;
        }
    }
}

extern "C" void kernel_launch(void* const* d_in, const int* in_sizes, int n_in,
                              void* d_out, int out_size, void* d_ws, size_t ws_size,
                              hipStream_t stream) {
    const float* x     = (const float*)d_in[0];
    const float* adj   = (const float*)d_in[1];
    const float* emb_w = (const float*)d_in[2];
    const float* gc1   = (const float*)d_in[3];
    const float* gc2   = (const float*)d_in[4];
    const float* gc3   = (const float*)d_in[5];
    const float* st_w1 = (const float*)d_in[6];
    const float* st_b1 = (const float*)d_in[7];
    const float* st_w2 = (const float*)d_in[8];
    const float* st_b2 = (const float*)d_in[9];
    const float* resc  = (const float*)d_in[10];
    float* out = (float*)d_out;
    float* ws  = (float*)d_ws;

    // workspace layout: T1 4.7MB | hA 12.6MB | hB 12.6MB | Sh 18.9MB | Sl 18.9MB = 67.7MB
    float* T1 = ws;                          // 1179648 f
    float* hA = T1 + 1179648;                // 3145728 f (h1, later h3)
    float* hB = hA + 3145728;                // 3145728 f (h2)
    _Float16* Sh = (_Float16*)(hB + 3145728);  // 9437184 halves
    _Float16* Sl = Sh + 9437184;               // 9437184 halves
    // Hh/Hl (h0 split, 64*16*384 halves each = 1.5 MB total) live in the hB region,
    // which is dead until k_zero before the first k_adj_mfma.
    _Float16* Hh = (_Float16*)hB;
    _Float16* Hl = Hh + 393216;

    // layer 1 (reassociated): h0 = x@emb^T (split fp16), T = adj@h0 via MFMA, h1 = sum_e relu(T@W1)
    k_h0split<<<96, 256, 0, stream>>>(x, emb_w, Hh, Hl);
    k_adj16<<<dim3(6, 3, 64), 256, 0, stream>>>(adj, Hh, Hl, T1);
    k_l1s2<<<384, 256, 0, stream>>>(T1, gc1, hA);
    // layer 2
    k_support<<<dim3(384, 3), 256, 0, stream>>>(hA, gc2, Sh, Sl);
    k_zero<<<3072, 256, 0, stream>>>(hB, 786432);
    k_adj_mfma<1><<<768, 256, 0, stream>>>(adj, Sh, Sl, hB);
    // layer 3 (no relu)
    k_support<<<dim3(384, 3), 256, 0, stream>>>(hB, gc3, Sh, Sl);
    k_zero<<<3072, 256, 0, stream>>>(hA, 786432);
    k_adj_mfma<0><<<768, 256, 0, stream>>>(adj, Sh, Sl, hA);
    // head
    k_head<<<384, 256, 0, stream>>>(hA, st_w1, st_b1, st_w2, st_b2, resc, out);
}

// Round 5
// 434.722 us; speedup vs baseline: 1.0993x; 1.0993x over previous
//
#include <hip/hip_runtime.h>
#include <math.h>

// Problem constants
// B=64, N=384, NFEAT=16, E=3, NHID=NOUT=128, ST_HID=64, ST_OUT=16
#define ROWS 24576            // B*N
#define ADJ_BE (384*384)      // per (b,e) adj matrix elems

typedef _Float16 h4v __attribute__((ext_vector_type(4)));
typedef _Float16 h8v __attribute__((ext_vector_type(8)));
typedef float f32x4 __attribute__((ext_vector_type(4)));

#define SPLIT_SCALE 2048.0f
#define INV_SPLIT_SCALE (1.0f / 2048.0f)

// ---------------- kernel 1a: h0 = x[b] @ emb^T, stored feature-major split-fp16 ----------------
__global__ __launch_bounds__(256) void k_h0split(const float* __restrict__ x,
        const float* __restrict__ emb_w, _Float16* __restrict__ Hh, _Float16* __restrict__ Hl) {
    __shared__ float embL[256];
    int t = threadIdx.x;
    if (t < 64) *(float4*)&embL[4 * t] = *(const float4*)(emb_w + 4 * t);
    __syncthreads();
    int gid = blockIdx.x * 256 + t;      // gid = b*384 + r
    int b = gid / 384, r = gid % 384;
    const float* xp = x + (size_t)gid * 16;
    float xr[16];
    *(float4*)&xr[0]  = *(const float4*)(xp);
    *(float4*)&xr[4]  = *(const float4*)(xp + 4);
    *(float4*)&xr[8]  = *(const float4*)(xp + 8);
    *(float4*)&xr[12] = *(const float4*)(xp + 12);
    size_t base = (size_t)b * 16 * 384 + r;
#pragma unroll
    for (int d = 0; d < 16; ++d) {
        float acc = 0.f;
#pragma unroll
        for (int k = 0; k < 16; ++k) acc = fmaf(xr[k], embL[d * 16 + k], acc);
        _Float16 h = (_Float16)acc;
        Hh[base + (size_t)d * 384] = h;
        Hl[base + (size_t)d * 384] = (_Float16)((acc - (float)h) * SPLIT_SCALE);
    }
}

// ---------------- kernel 1b: T[b,e] = adj[b,e] @ h0[b] via scaled-split fp16 MFMA ----------------
// 64-row tiles, grid (6 mt, 3 e, 64 b) = 1152 blocks. Reg-staged software pipeline.
// l16 dim padded 16->17: quad-stride 256B->272B, staging writes/reads <=2-way banks.
__global__ __launch_bounds__(256) void k_adj16(const float* __restrict__ adj,
        const _Float16* __restrict__ Hh, const _Float16* __restrict__ Hl,
        float* __restrict__ T1) {
    int mt = blockIdx.x, e = blockIdx.y, b = blockIdx.z;
    const float* A = adj + (size_t)(b * 3 + e) * ADJ_BE + (size_t)mt * 64 * 384;
    const _Float16* BH = Hh + (size_t)b * 16 * 384;
    const _Float16* BL = Hl + (size_t)b * 16 * 384;

    __shared__ _Float16 Af[2][4][4][17][8];   // 8.7 KB (64 rows x 32 k, hi+lo, padded)

    int t = threadIdx.x;
    int wave = t >> 6, lane = t & 63;
    int l16 = lane & 15, quad = lane >> 4;
    int r0s = t >> 3, q4s = t & 7;

    f32x4 acc0 = f32x4{0.f, 0.f, 0.f, 0.f};
    f32x4 acc1 = f32x4{0.f, 0.f, 0.f, 0.f};

    float4 ra[2];
    h8v rbh, rbl;
#pragma unroll
    for (int p = 0; p < 2; ++p)
        ra[p] = *(const float4*)(A + (size_t)(r0s + 32 * p) * 384 + 4 * q4s);
    rbh = *(const h8v*)(BH + (size_t)l16 * 384 + 8 * quad);
    rbl = *(const h8v*)(BL + (size_t)l16 * 384 + 8 * quad);

    for (int kc = 0; kc < 12; ++kc) {
#pragma unroll
        for (int p = 0; p < 2; ++p) {
            int r = r0s + 32 * p;
            float vv[4] = {ra[p].x, ra[p].y, ra[p].z, ra[p].w};
            h4v hh, ll;
#pragma unroll
            for (int c = 0; c < 4; ++c) {
                _Float16 h = (_Float16)vv[c];
                hh[c] = h;
                ll[c] = (_Float16)((vv[c] - (float)h) * SPLIT_SCALE);
            }
            *(h4v*)&Af[0][r >> 4][q4s >> 1][r & 15][(q4s & 1) * 4] = hh;
            *(h4v*)&Af[1][r >> 4][q4s >> 1][r & 15][(q4s & 1) * 4] = ll;
        }
        h8v b_h = rbh, b_l = rbl;
        __syncthreads();
        if (kc + 1 < 12) {
            int kn = (kc + 1) * 32;
#pragma unroll
            for (int p = 0; p < 2; ++p)
                ra[p] = *(const float4*)(A + (size_t)(r0s + 32 * p) * 384 + kn + 4 * q4s);
            rbh = *(const h8v*)(BH + (size_t)l16 * 384 + kn + 8 * quad);
            rbl = *(const h8v*)(BL + (size_t)l16 * 384 + kn + 8 * quad);
        }
        h8v a_h = *(const h8v*)&Af[0][wave][quad][l16][0];
        h8v a_l = *(const h8v*)&Af[1][wave][quad][l16][0];
        acc0 = __builtin_amdgcn_mfma_f32_16x16x32_f16(a_h, b_h, acc0, 0, 0, 0);
        acc1 = __builtin_amdgcn_mfma_f32_16x16x32_f16(a_h, b_l, acc1, 0, 0, 0);
        acc1 = __builtin_amdgcn_mfma_f32_16x16x32_f16(a_l, b_h, acc1, 0, 0, 0);
        __syncthreads();
    }
    float* Tp = T1 + ((size_t)(b * 3 + e) * 384 + (size_t)mt * 64 + wave * 16) * 16;
#pragma unroll
    for (int reg = 0; reg < 4; ++reg) {
        float v = fmaf(acc1[reg], INV_SPLIT_SCALE, acc0[reg]);
        Tp[(quad * 4 + reg) * 16 + l16] = v;
    }
}

// ---------------- kernel 2: h1 = sum_e relu(T[b,e] @ W1[e])  (K=16) ----------------
__global__ __launch_bounds__(256) void k_l1s2(const float* __restrict__ T1,
        const float* __restrict__ W1, float* __restrict__ h1) {
    __shared__ float wL[3][16][128];
    __shared__ float tL[3][64][17];
    int t = threadIdx.x;
    int rt = blockIdx.x;             // 64-row tile of flattened (b*384+m)
    int b = rt / 6, m0 = (rt % 6) * 64;
#pragma unroll
    for (int p = 0; p < 6; ++p) {    // W1: 3*16*128 floats = 1536 f4
        int idx = t + p * 256;
        float4 v = *(const float4*)(W1 + (size_t)idx * 4);
        int e = idx / 512, rem = idx % 512;
        int d = rem >> 5, q = rem & 31;
        *(float4*)&wL[e][d][q * 4] = v;
    }
#pragma unroll
    for (int p = 0; p < 3; ++p) {    // T tiles: 3*64*16 = 768 f4
        int idx = t + p * 256;
        int e = idx >> 8, rem = idx & 255;
        int r = rem >> 2, q = rem & 3;
        float4 v = *(const float4*)(T1 + ((size_t)(b * 3 + e) * 384 + m0 + r) * 16 + q * 4);
        tL[e][r][q*4+0] = v.x; tL[e][r][q*4+1] = v.y; tL[e][r][q*4+2] = v.z; tL[e][r][q*4+3] = v.w;
    }
    __syncthreads();
    int tx = t & 31;                 // cols c = tx + 32j, j<4
    int ty = t >> 5;                 // rows r = ty + 8i, i<8
    float tot[8][4] = {};
#pragma unroll
    for (int e = 0; e < 3; ++e) {
        float acc[8][4] = {};
#pragma unroll
        for (int d = 0; d < 16; ++d) {
            float a[8], w[4];
#pragma unroll
            for (int i = 0; i < 8; ++i) a[i] = tL[e][ty + 8 * i][d];
#pragma unroll
            for (int j = 0; j < 4; ++j) w[j] = wL[e][d][tx + 32 * j];
#pragma unroll
            for (int i = 0; i < 8; ++i)
#pragma unroll
                for (int j = 0; j < 4; ++j)
                    acc[i][j] = fmaf(a[i], w[j], acc[i][j]);
        }
#pragma unroll
        for (int i = 0; i < 8; ++i)
#pragma unroll
            for (int j = 0; j < 4; ++j)
                tot[i][j] += fmaxf(acc[i][j], 0.f);
    }
    float* out = h1 + (size_t)rt * 64 * 128;
#pragma unroll
    for (int i = 0; i < 8; ++i)
#pragma unroll
        for (int j = 0; j < 4; ++j)
            out[(ty + 8 * i) * 128 + tx + 32 * j] = tot[i][j];
}

// ---------------- kernel 3: S_t hi/lo fp16 = (h[b] @ W[e])^T  (64x128 tile, K=128) ----------------
__global__ __launch_bounds__(256) void k_support(const float* __restrict__ hin,
        const float* __restrict__ W, _Float16* __restrict__ Sh, _Float16* __restrict__ Sl) {
    int rt = blockIdx.x, e = blockIdx.y;
    int b = rt / 6, n0 = (rt % 6) * 64;   // n0 = node-index tile base (the k of the adj-gemm)
    const float* Hp = hin + (size_t)rt * 64 * 128;
    const float* Wp = W + (size_t)e * 128 * 128;
    __shared__ float aT[32][68];    // [k][row]
    __shared__ float bT[32][132];   // [k][col]
    int t = threadIdx.x;
    int tx = t & 15;                // cols {4tx..4tx+3, 64+4tx..}
    int ty = t >> 4;                // rows 4ty..4ty+3
    float acc[4][8] = {};
    for (int k0 = 0; k0 < 128; k0 += 32) {
        __syncthreads();
#pragma unroll
        for (int p = 0; p < 2; ++p) {          // h tile 64x32 transposed (512 f4)
            int idx = t + p * 256;
            int r = idx >> 3, q = idx & 7;
            float4 v = *(const float4*)(Hp + (size_t)r * 128 + k0 + q * 4);
            aT[q*4+0][r] = v.x; aT[q*4+1][r] = v.y; aT[q*4+2][r] = v.z; aT[q*4+3][r] = v.w;
        }
#pragma unroll
        for (int p = 0; p < 4; ++p) {          // W tile 32x128 (1024 f4)
            int idx = t + p * 256;
            int r = idx >> 5, q = idx & 31;
            *(float4*)&bT[r][q * 4] = *(const float4*)(Wp + (size_t)(k0 + r) * 128 + q * 4);
        }
        __syncthreads();
#pragma unroll
        for (int k = 0; k < 32; ++k) {
            float4 av = *(const float4*)&aT[k][4 * ty];
            float4 b0 = *(const float4*)&bT[k][4 * tx];
            float4 b1 = *(const float4*)&bT[k][64 + 4 * tx];
            float a[4] = {av.x, av.y, av.z, av.w};
            float bb[8] = {b0.x, b0.y, b0.z, b0.w, b1.x, b1.y, b1.z, b1.w};
#pragma unroll
            for (int i = 0; i < 4; ++i)
#pragma unroll
                for (int j = 0; j < 8; ++j)
                    acc[i][j] = fmaf(a[i], bb[j], acc[i][j]);
        }
    }
    size_t base = (size_t)(b * 3 + e) * 128 * 384;
#pragma unroll
    for (int j = 0; j < 8; ++j) {
        int n = (j < 4) ? (4 * tx + j) : (64 + 4 * tx + j - 4);
        h4v hh, ll;
#pragma unroll
        for (int i = 0; i < 4; ++i) {
            float v = acc[i][j];
            _Float16 h = (_Float16)v;
            hh[i] = h;
            ll[i] = (_Float16)((v - (float)h) * SPLIT_SCALE);
        }
        size_t off = base + (size_t)n * 384 + n0 + 4 * ty;
        *(h4v*)(Sh + off) = hh;
        *(h4v*)(Sl + off) = ll;
    }
}

// ---------------- kernel 4: out[b] += relu?(adj[b,e] @ S[b,e]) via scaled-split fp16 MFMA ----------------
// 96x128 block tile, XCD-swizzled 1D grid of 768: xcd = bid&7, l = bid>>3;
// pair = xcd*24 + (l>>2) (= b*3+e), mt = l&3. All 4 mt-blocks sharing one S(b,e)
// panel land on the same XCD -> S re-reads hit local L2.
// Reg-staged software pipeline (T14). l16 dim padded 16->17 (quad-stride 272B):
// staging writes and fragment reads <=2-way bank conflicts (was 4-way).
// acc0 = ah*Sh; acc1 = ah*Sl' + al'*Sh (scale 2^11); result = acc0 + acc1/2048.
template <int RELU>
__global__ __launch_bounds__(256, 3) void k_adj_mfma(const float* __restrict__ adj,
        const _Float16* __restrict__ Sh, const _Float16* __restrict__ Sl,
        float* __restrict__ out) {
    int bid = blockIdx.x;
    int xcd = bid & 7, l = bid >> 3;
    int pair = xcd * 24 + (l >> 2);           // 0..191 == b*3+e  (bijective)
    int mt = l & 3;
    int b = pair / 3;
    const float* A = adj + (size_t)pair * ADJ_BE + (size_t)mt * 96 * 384;
    const _Float16* Bh = Sh + (size_t)pair * 128 * 384;
    const _Float16* Bl = Sl + (size_t)pair * 128 * 384;
    float* O = out + ((size_t)b * 384 + mt * 96) * 128;

    // fragment-linear LDS, padded: [plane][subtile][quad(k8)][l16 pad 17][8 halves]
    __shared__ _Float16 Af[2][6][4][17][8];   // 12.75 KB  (96 rows x 32 k)
    __shared__ _Float16 Bf[2][8][4][17][8];   // 17 KB     (128 cols x 32 k)

    int t = threadIdx.x;
    int wave = t >> 6, lane = t & 63;
    int l16 = lane & 15, quad = lane >> 4;
    int wm = wave >> 1, wn = wave & 1;        // wave tile: rows 48*wm.., cols 64*wn..
    int r0s = t >> 3, q4s = t & 7;            // A staging: row (p adds 32), 4-float k-group

    f32x4 acc0[3][4], acc1[3][4];
#pragma unroll
    for (int i = 0; i < 3; ++i)
#pragma unroll
        for (int j = 0; j < 4; ++j) {
            acc0[i][j] = f32x4{0.f, 0.f, 0.f, 0.f};
            acc1[i][j] = f32x4{0.f, 0.f, 0.f, 0.f};
        }

    float4 ra[3];                             // A prefetch: 96x32 f32 = 768 f4, 3/thread
    h8v rb[4];                                // B prefetch: 2 planes x 512 h8v, 4/thread
    // prologue: prefetch chunk 0
#pragma unroll
    for (int p = 0; p < 3; ++p)
        ra[p] = *(const float4*)(A + (size_t)(r0s + 32 * p) * 384 + 4 * q4s);
#pragma unroll
    for (int p = 0; p < 4; ++p) {
        int si = t + 256 * (p & 1);
        int n = si >> 2, q8 = si & 3;
        const _Float16* Bsrc = (p < 2) ? Bh : Bl;
        rb[p] = *(const h8v*)(Bsrc + (size_t)n * 384 + 8 * q8);
    }

    for (int k0 = 0; k0 < 384; k0 += 32) {
        // stage from regs into LDS (cvt for A; straight copy for B)
#pragma unroll
        for (int p = 0; p < 3; ++p) {
            int r = r0s + 32 * p;
            float vv[4] = {ra[p].x, ra[p].y, ra[p].z, ra[p].w};
            h4v hh, ll;
#pragma unroll
            for (int c = 0; c < 4; ++c) {
                _Float16 h = (_Float16)vv[c];
                hh[c] = h;
                ll[c] = (_Float16)((vv[c] - (float)h) * SPLIT_SCALE);
            }
            *(h4v*)&Af[0][r >> 4][q4s >> 1][r & 15][(q4s & 1) * 4] = hh;
            *(h4v*)&Af[1][r >> 4][q4s >> 1][r & 15][(q4s & 1) * 4] = ll;
        }
#pragma unroll
        for (int p = 0; p < 4; ++p) {
            int si = t + 256 * (p & 1);
            int n = si >> 2, q8 = si & 3;
            *(h8v*)&Bf[p >> 1][n >> 4][q8][n & 15][0] = rb[p];
        }
        __syncthreads();
        if (k0 + 32 < 384) {                  // issue next chunk's loads (overlap with MFMA)
            int kn = k0 + 32;
#pragma unroll
            for (int p = 0; p < 3; ++p)
                ra[p] = *(const float4*)(A + (size_t)(r0s + 32 * p) * 384 + kn + 4 * q4s);
#pragma unroll
            for (int p = 0; p < 4; ++p) {
                int si = t + 256 * (p & 1);
                int n = si >> 2, q8 = si & 3;
                const _Float16* Bsrc = (p < 2) ? Bh : Bl;
                rb[p] = *(const h8v*)(Bsrc + (size_t)n * 384 + kn + 8 * q8);
            }
        }
        // A fragments (reused across j)
        h8v a_h[3], a_l[3];
#pragma unroll
        for (int i = 0; i < 3; ++i) {
            a_h[i] = *(const h8v*)&Af[0][3 * wm + i][quad][l16][0];
            a_l[i] = *(const h8v*)&Af[1][3 * wm + i][quad][l16][0];
        }
#pragma unroll
        for (int j = 0; j < 4; ++j) {
            h8v b_h = *(const h8v*)&Bf[0][4 * wn + j][quad][l16][0];
            h8v b_l = *(const h8v*)&Bf[1][4 * wn + j][quad][l16][0];
#pragma unroll
            for (int i = 0; i < 3; ++i) {
                acc0[i][j] = __builtin_amdgcn_mfma_f32_16x16x32_f16(a_h[i], b_h, acc0[i][j], 0, 0, 0);
                acc1[i][j] = __builtin_amdgcn_mfma_f32_16x16x32_f16(a_h[i], b_l, acc1[i][j], 0, 0, 0);
                acc1[i][j] = __builtin_amdgcn_mfma_f32_16x16x32_f16(a_l[i], b_h, acc1[i][j], 0, 0, 0);
            }
        }
        __syncthreads();
    }
    // epilogue: C/D layout col=lane&15, row=quad*4+reg. Contiguous 16-lane atomics.
#pragma unroll
    for (int i = 0; i < 3; ++i) {
        int r0 = 48 * wm + 16 * i + quad * 4;
#pragma unroll
        for (int j = 0; j < 4; ++j) {
            int gc = 64 * wn + 16 * j + l16;
#pragma unroll
            for (int reg = 0; reg < 4; ++reg) {
                float v = fmaf(acc1[i][j][reg], INV_SPLIT_SCALE, acc0[i][j][reg]);
                if (RELU) v = fmaxf(v, 0.f);
                atomicAdd(O + (size_t)(r0 + reg) * 128 + gc, v);
            }
        }
    }
}

// ---------------- zero helper ----------------
__global__ void k_zero(float* __restrict__ p, int n4) {
    int i = blockIdx.x * blockDim.x + threadIdx.x;
    if (i < n4) ((float4*)p)[i] = float4{0.f, 0.f, 0.f, 0.f};
}

// ---------------- kernel 5: fused head ----------------
__global__ __launch_bounds__(256) void k_head(const float* __restrict__ h3,
        const float* __restrict__ st_w1, const float* __restrict__ st_b1,
        const float* __restrict__ st_w2, const float* __restrict__ st_b2,
        const float* __restrict__ rescale_w, float* __restrict__ out) {
    __shared__ float hL[64][132];
    __shared__ float w1L[64][132];
    __shared__ float ytL[64][68];
    __shared__ float w2L[32][68];
    __shared__ float b1L[64], b2L[32];
    int t = threadIdx.x;
    int r0 = blockIdx.x * 64;
#pragma unroll
    for (int p = 0; p < 8; ++p) {   // h rows 64x128 = 2048 f4
        int idx = t + p * 256;
        int r = idx >> 5, q = idx & 31;
        *(float4*)&hL[r][q * 4] = *(const float4*)(h3 + (size_t)(r0 + r) * 128 + q * 4);
    }
#pragma unroll
    for (int p = 0; p < 8; ++p) {   // w1 64x128
        int idx = t + p * 256;
        int r = idx >> 5, q = idx & 31;
        *(float4*)&w1L[r][q * 4] = *(const float4*)(st_w1 + (size_t)r * 128 + q * 4);
    }
#pragma unroll
    for (int p = 0; p < 2; ++p) {   // w2 32x64 = 512 f4
        int idx = t + p * 256;
        int r = idx >> 4, q = idx & 15;
        *(float4*)&w2L[r][q * 4] = *(const float4*)(st_w2 + (size_t)r * 64 + q * 4);
    }
    if (t < 64) b1L[t] = st_b1[t];
    else if (t < 96) b2L[t - 64] = st_b2[t - 64];
    __syncthreads();
    // phase 1: y = h @ w1^T + b1, tanh
    int tx = t & 15, ty = t >> 4;
    float acc[4][4] = {};
    for (int d = 0; d < 128; ++d) {
        float a[4], w[4];
#pragma unroll
        for (int i = 0; i < 4; ++i) a[i] = hL[ty + 16 * i][d];
#pragma unroll
        for (int j = 0; j < 4; ++j) w[j] = w1L[tx + 16 * j][d];
#pragma unroll
        for (int i = 0; i < 4; ++i)
#pragma unroll
            for (int j = 0; j < 4; ++j)
                acc[i][j] = fmaf(a[i], w[j], acc[i][j]);
    }
#pragma unroll
    for (int i = 0; i < 4; ++i)
#pragma unroll
        for (int j = 0; j < 4; ++j)
            ytL[ty + 16 * i][tx + 16 * j] = tanhf(acc[i][j] + b1L[tx + 16 * j]);
    __syncthreads();
    // phase 2: z = yt @ w2^T + b2; split into s (tanh*exp(rescale)) and t
    int tx8 = t & 7, ty32 = t >> 3;
    float acc2[2][4] = {};
    for (int d = 0; d < 64; ++d) {
        float a[2], w[4];
#pragma unroll
        for (int i = 0; i < 2; ++i) a[i] = ytL[ty32 + 32 * i][d];
#pragma unroll
        for (int j = 0; j < 4; ++j) w[j] = w2L[tx8 + 8 * j][d];
#pragma unroll
        for (int i = 0; i < 2; ++i)
#pragma unroll
            for (int j = 0; j < 4; ++j)
                acc2[i][j] = fmaf(a[i], w[j], acc2[i][j]);
    }
    float er = expf(rescale_w[0]);
#pragma unroll
    for (int i = 0; i < 2; ++i) {
        int r = r0 + ty32 + 32 * i;
#pragma unroll
        for (int j = 0; j < 4; ++j) {
            int c = tx8 + 8 * j;
            float z = acc2[i][j] + b2L[c];
            if (c < 16) out[(size_t)r * 16 + c] = er * tanhf(z);
            else        out[(size_t)(ROWS + r) * 16 + (c - 16)] = z;
        }
    }
}

extern "C" void kernel_launch(void* const* d_in, const int* in_sizes, int n_in,
                              void* d_out, int out_size, void* d_ws, size_t ws_size,
                              hipStream_t stream) {
    const float* x     = (const float*)d_in[0];
    const float* adj   = (const float*)d_in[1];
    const float* emb_w = (const float*)d_in[2];
    const float* gc1   = (const float*)d_in[3];
    const float* gc2   = (const float*)d_in[4];
    const float* gc3   = (const float*)d_in[5];
    const float* st_w1 = (const float*)d_in[6];
    const float* st_b1 = (const float*)d_in[7];
    const float* st_w2 = (const float*)d_in[8];
    const float* st_b2 = (const float*)d_in[9];
    const float* resc  = (const float*)d_in[10];
    float* out = (float*)d_out;
    float* ws  = (float*)d_ws;

    // workspace layout: T1 4.7MB | hA 12.6MB | hB 12.6MB | Sh 18.9MB | Sl 18.9MB = 67.7MB
    float* T1 = ws;                          // 1179648 f
    float* hA = T1 + 1179648;                // 3145728 f (h1, later h3)
    float* hB = hA + 3145728;                // 3145728 f (h2)
    _Float16* Sh = (_Float16*)(hB + 3145728);  // 9437184 halves
    _Float16* Sl = Sh + 9437184;               // 9437184 halves
    // Hh/Hl (h0 split, 64*16*384 halves each = 1.5 MB total) live in the hB region,
    // which is dead until k_zero before the first k_adj_mfma.
    _Float16* Hh = (_Float16*)hB;
    _Float16* Hl = Hh + 393216;

    // layer 1 (reassociated): h0 = x@emb^T (split fp16), T = adj@h0 via MFMA, h1 = sum_e relu(T@W1)
    k_h0split<<<96, 256, 0, stream>>>(x, emb_w, Hh, Hl);
    k_adj16<<<dim3(6, 3, 64), 256, 0, stream>>>(adj, Hh, Hl, T1);
    k_l1s2<<<384, 256, 0, stream>>>(T1, gc1, hA);
    // layer 2
    k_support<<<dim3(384, 3), 256, 0, stream>>>(hA, gc2, Sh, Sl);
    k_zero<<<3072, 256, 0, stream>>>(hB, 786432);
    k_adj_mfma<1><<<768, 256, 0, stream>>>(adj, Sh, Sl, hB);
    // layer 3 (no relu)
    k_support<<<dim3(384, 3), 256, 0, stream>>>(hB, gc3, Sh, Sl);
    k_zero<<<3072, 256, 0, stream>>>(hA, 786432);
    k_adj_mfma<0><<<768, 256, 0, stream>>>(adj, Sh, Sl, hA);
    // head
    k_head<<<384, 256, 0, stream>>>(hA, st_w1, st_b1, st_w2, st_b2, resc, out);
}

// Round 8
// 371.619 us; speedup vs baseline: 1.2859x; 1.1698x over previous
//
#include <hip/hip_runtime.h>
#include <math.h>

// Problem constants
// B=64, N=384, NFEAT=16, E=3, NHID=NOUT=128, ST_HID=64, ST_OUT=16
#define ROWS 24576            // B*N
#define ADJ_BE (384*384)      // per (b,e) adj matrix elems

typedef _Float16 h4v __attribute__((ext_vector_type(4)));
typedef _Float16 h8v __attribute__((ext_vector_type(8)));
typedef float f32x4 __attribute__((ext_vector_type(4)));

#define SPLIT_SCALE 2048.0f
#define INV_SPLIT_SCALE (1.0f / 2048.0f)

// ---------------- kernel 1a: h0 = x[b] @ emb^T, stored feature-major split-fp16 ----------------
__global__ __launch_bounds__(256) void k_h0split(const float* __restrict__ x,
        const float* __restrict__ emb_w, _Float16* __restrict__ Hh, _Float16* __restrict__ Hl) {
    __shared__ float embL[256];
    int t = threadIdx.x;
    if (t < 64) *(float4*)&embL[4 * t] = *(const float4*)(emb_w + 4 * t);
    __syncthreads();
    int gid = blockIdx.x * 256 + t;      // gid = b*384 + r
    int b = gid / 384, r = gid % 384;
    const float* xp = x + (size_t)gid * 16;
    float xr[16];
    *(float4*)&xr[0]  = *(const float4*)(xp);
    *(float4*)&xr[4]  = *(const float4*)(xp + 4);
    *(float4*)&xr[8]  = *(const float4*)(xp + 8);
    *(float4*)&xr[12] = *(const float4*)(xp + 12);
    size_t base = (size_t)b * 16 * 384 + r;
#pragma unroll
    for (int d = 0; d < 16; ++d) {
        float acc = 0.f;
#pragma unroll
        for (int k = 0; k < 16; ++k) acc = fmaf(xr[k], embL[d * 16 + k], acc);
        _Float16 h = (_Float16)acc;
        Hh[base + (size_t)d * 384] = h;
        Hl[base + (size_t)d * 384] = (_Float16)((acc - (float)h) * SPLIT_SCALE);
    }
}

// ---------------- kernel 1b: T[b,e] = adj[b,e] @ h0[b] via scaled-split fp16 MFMA ----------------
// 64-row tiles, grid (6 mt, 3 e, 64 b) = 1152 blocks. Reg-staged software pipeline.
// l16 dim padded 16->17: quad-stride 256B->272B, staging writes/reads <=2-way banks.
__global__ __launch_bounds__(256) void k_adj16(const float* __restrict__ adj,
        const _Float16* __restrict__ Hh, const _Float16* __restrict__ Hl,
        float* __restrict__ T1) {
    int mt = blockIdx.x, e = blockIdx.y, b = blockIdx.z;
    const float* A = adj + (size_t)(b * 3 + e) * ADJ_BE + (size_t)mt * 64 * 384;
    const _Float16* BH = Hh + (size_t)b * 16 * 384;
    const _Float16* BL = Hl + (size_t)b * 16 * 384;

    __shared__ _Float16 Af[2][4][4][17][8];   // 8.7 KB (64 rows x 32 k, hi+lo, padded)

    int t = threadIdx.x;
    int wave = t >> 6, lane = t & 63;
    int l16 = lane & 15, quad = lane >> 4;
    int r0s = t >> 3, q4s = t & 7;

    f32x4 acc0 = f32x4{0.f, 0.f, 0.f, 0.f};
    f32x4 acc1 = f32x4{0.f, 0.f, 0.f, 0.f};

    float4 ra[2];
    h8v rbh, rbl;
#pragma unroll
    for (int p = 0; p < 2; ++p)
        ra[p] = *(const float4*)(A + (size_t)(r0s + 32 * p) * 384 + 4 * q4s);
    rbh = *(const h8v*)(BH + (size_t)l16 * 384 + 8 * quad);
    rbl = *(const h8v*)(BL + (size_t)l16 * 384 + 8 * quad);

    for (int kc = 0; kc < 12; ++kc) {
#pragma unroll
        for (int p = 0; p < 2; ++p) {
            int r = r0s + 32 * p;
            float vv[4] = {ra[p].x, ra[p].y, ra[p].z, ra[p].w};
            h4v hh, ll;
#pragma unroll
            for (int c = 0; c < 4; ++c) {
                _Float16 h = (_Float16)vv[c];
                hh[c] = h;
                ll[c] = (_Float16)((vv[c] - (float)h) * SPLIT_SCALE);
            }
            *(h4v*)&Af[0][r >> 4][q4s >> 1][r & 15][(q4s & 1) * 4] = hh;
            *(h4v*)&Af[1][r >> 4][q4s >> 1][r & 15][(q4s & 1) * 4] = ll;
        }
        h8v b_h = rbh, b_l = rbl;
        __syncthreads();
        if (kc + 1 < 12) {
            int kn = (kc + 1) * 32;
#pragma unroll
            for (int p = 0; p < 2; ++p)
                ra[p] = *(const float4*)(A + (size_t)(r0s + 32 * p) * 384 + kn + 4 * q4s);
            rbh = *(const h8v*)(BH + (size_t)l16 * 384 + kn + 8 * quad);
            rbl = *(const h8v*)(BL + (size_t)l16 * 384 + kn + 8 * quad);
        }
        h8v a_h = *(const h8v*)&Af[0][wave][quad][l16][0];
        h8v a_l = *(const h8v*)&Af[1][wave][quad][l16][0];
        acc0 = __builtin_amdgcn_mfma_f32_16x16x32_f16(a_h, b_h, acc0, 0, 0, 0);
        acc1 = __builtin_amdgcn_mfma_f32_16x16x32_f16(a_h, b_l, acc1, 0, 0, 0);
        acc1 = __builtin_amdgcn_mfma_f32_16x16x32_f16(a_l, b_h, acc1, 0, 0, 0);
        __syncthreads();
    }
    float* Tp = T1 + ((size_t)(b * 3 + e) * 384 + (size_t)mt * 64 + wave * 16) * 16;
#pragma unroll
    for (int reg = 0; reg < 4; ++reg) {
        float v = fmaf(acc1[reg], INV_SPLIT_SCALE, acc0[reg]);
        Tp[(quad * 4 + reg) * 16 + l16] = v;
    }
}

// ---------------- kernel 2: h1 = sum_e relu(T[b,e] @ W1[e])  (K=16) ----------------
__global__ __launch_bounds__(256) void k_l1s2(const float* __restrict__ T1,
        const float* __restrict__ W1, float* __restrict__ h1) {
    __shared__ float wL[3][16][128];
    __shared__ float tL[3][64][17];
    int t = threadIdx.x;
    int rt = blockIdx.x;             // 64-row tile of flattened (b*384+m)
    int b = rt / 6, m0 = (rt % 6) * 64;
#pragma unroll
    for (int p = 0; p < 6; ++p) {    // W1: 3*16*128 floats = 1536 f4
        int idx = t + p * 256;
        float4 v = *(const float4*)(W1 + (size_t)idx * 4);
        int e = idx / 512, rem = idx % 512;
        int d = rem >> 5, q = rem & 31;
        *(float4*)&wL[e][d][q * 4] = v;
    }
#pragma unroll
    for (int p = 0; p < 3; ++p) {    // T tiles: 3*64*16 = 768 f4
        int idx = t + p * 256;
        int e = idx >> 8, rem = idx & 255;
        int r = rem >> 2, q = rem & 3;
        float4 v = *(const float4*)(T1 + ((size_t)(b * 3 + e) * 384 + m0 + r) * 16 + q * 4);
        tL[e][r][q*4+0] = v.x; tL[e][r][q*4+1] = v.y; tL[e][r][q*4+2] = v.z; tL[e][r][q*4+3] = v.w;
    }
    __syncthreads();
    int tx = t & 31;                 // cols c = tx + 32j, j<4
    int ty = t >> 5;                 // rows r = ty + 8i, i<8
    float tot[8][4] = {};
#pragma unroll
    for (int e = 0; e < 3; ++e) {
        float acc[8][4] = {};
#pragma unroll
        for (int d = 0; d < 16; ++d) {
            float a[8], w[4];
#pragma unroll
            for (int i = 0; i < 8; ++i) a[i] = tL[e][ty + 8 * i][d];
#pragma unroll
            for (int j = 0; j < 4; ++j) w[j] = wL[e][d][tx + 32 * j];
#pragma unroll
            for (int i = 0; i < 8; ++i)
#pragma unroll
                for (int j = 0; j < 4; ++j)
                    acc[i][j] = fmaf(a[i], w[j], acc[i][j]);
        }
#pragma unroll
        for (int i = 0; i < 8; ++i)
#pragma unroll
            for (int j = 0; j < 4; ++j)
                tot[i][j] += fmaxf(acc[i][j], 0.f);
    }
    float* out = h1 + (size_t)rt * 64 * 128;
#pragma unroll
    for (int i = 0; i < 8; ++i)
#pragma unroll
        for (int j = 0; j < 4; ++j)
            out[(ty + 8 * i) * 128 + tx + 32 * j] = tot[i][j];
}

// ---------------- kernel 3: S_t hi/lo fp16 = (h[b] @ W[e])^T  (64x128 tile, K=128) ----------------
__global__ __launch_bounds__(256) void k_support(const float* __restrict__ hin,
        const float* __restrict__ W, _Float16* __restrict__ Sh, _Float16* __restrict__ Sl) {
    int rt = blockIdx.x, e = blockIdx.y;
    int b = rt / 6, n0 = (rt % 6) * 64;   // n0 = node-index tile base (the k of the adj-gemm)
    const float* Hp = hin + (size_t)rt * 64 * 128;
    const float* Wp = W + (size_t)e * 128 * 128;
    __shared__ float aT[32][68];    // [k][row]
    __shared__ float bT[32][132];   // [k][col]
    int t = threadIdx.x;
    int tx = t & 15;                // cols {4tx..4tx+3, 64+4tx..}
    int ty = t >> 4;                // rows 4ty..4ty+3
    float acc[4][8] = {};
    for (int k0 = 0; k0 < 128; k0 += 32) {
        __syncthreads();
#pragma unroll
        for (int p = 0; p < 2; ++p) {          // h tile 64x32 transposed (512 f4)
            int idx = t + p * 256;
            int r = idx >> 3, q = idx & 7;
            float4 v = *(const float4*)(Hp + (size_t)r * 128 + k0 + q * 4);
            aT[q*4+0][r] = v.x; aT[q*4+1][r] = v.y; aT[q*4+2][r] = v.z; aT[q*4+3][r] = v.w;
        }
#pragma unroll
        for (int p = 0; p < 4; ++p) {          // W tile 32x128 (1024 f4)
            int idx = t + p * 256;
            int r = idx >> 5, q = idx & 31;
            *(float4*)&bT[r][q * 4] = *(const float4*)(Wp + (size_t)(k0 + r) * 128 + q * 4);
        }
        __syncthreads();
#pragma unroll
        for (int k = 0; k < 32; ++k) {
            float4 av = *(const float4*)&aT[k][4 * ty];
            float4 b0 = *(const float4*)&bT[k][4 * tx];
            float4 b1 = *(const float4*)&bT[k][64 + 4 * tx];
            float a[4] = {av.x, av.y, av.z, av.w};
            float bb[8] = {b0.x, b0.y, b0.z, b0.w, b1.x, b1.y, b1.z, b1.w};
#pragma unroll
            for (int i = 0; i < 4; ++i)
#pragma unroll
                for (int j = 0; j < 8; ++j)
                    acc[i][j] = fmaf(a[i], bb[j], acc[i][j]);
        }
    }
    size_t base = (size_t)(b * 3 + e) * 128 * 384;
#pragma unroll
    for (int j = 0; j < 8; ++j) {
        int n = (j < 4) ? (4 * tx + j) : (64 + 4 * tx + j - 4);
        h4v hh, ll;
#pragma unroll
        for (int i = 0; i < 4; ++i) {
            float v = acc[i][j];
            _Float16 h = (_Float16)v;
            hh[i] = h;
            ll[i] = (_Float16)((v - (float)h) * SPLIT_SCALE);
        }
        size_t off = base + (size_t)n * 384 + n0 + 4 * ty;
        *(h4v*)(Sh + off) = hh;
        *(h4v*)(Sl + off) = ll;
    }
}

// ---------------- kernel 4: out[b] = sum_e relu?(adj[b,e] @ S[b,e]) — e-FUSED, no atomics ----------------
// 48x128 output tile per block, grid 512 (2.0/CU). Flat 36-chunk K-loop over (e, K=384).
// PER-E RELU (matches reference: relu per relation, THEN sum over e): at each relation
// boundary (c%12==11) fold acc0+acc1/2048 into tot with optional relu, reset accumulators.
// Single plain-store epilogue (no k_zero, no atomicAdd).
// XCD swizzle: xcd = bid&7, l = bid>>3, b = xcd*8 + (l>>3), mt = l&7 -> all 8 mt-blocks of
// one b on one XCD; per-e S working set/XCD = 8 x 192 KB = 1.5 MB (L2-fits).
// 4 waves: wave w owns cols 32w..32w+31 (2 j-subtiles), all 48 rows (3 i-subtiles) = 18 MFMA/chunk.
// Reg-staged pipeline + padded LDS (l16 dim 17) as validated in R2/R4.
template <int RELU>
__global__ __launch_bounds__(256, 2) void k_adj_fused(const float* __restrict__ adj,
        const _Float16* __restrict__ Sh, const _Float16* __restrict__ Sl,
        float* __restrict__ out) {
    int bid = blockIdx.x;
    int xcd = bid & 7, l = bid >> 3;
    int b = xcd * 8 + (l >> 3);               // 0..63 (bijective)
    int mt = l & 7;                           // 48-row tile index
    const float* A0 = adj + (size_t)(b * 3) * ADJ_BE + (size_t)mt * 48 * 384;
    const _Float16* Bh0 = Sh + (size_t)(b * 3) * 128 * 384;
    const _Float16* Bl0 = Sl + (size_t)(b * 3) * 128 * 384;
    float* O = out + ((size_t)b * 384 + mt * 48) * 128;

    // padded fragment-linear LDS: [plane][subtile][quad(k8)][l16 pad 17][8 halves]
    __shared__ _Float16 Af[2][3][4][17][8];   // 6.4 KB (48 rows x 32 k)
    __shared__ _Float16 Bf[2][8][4][17][8];   // 17 KB  (128 cols x 32 k)

    int t = threadIdx.x;
    int wave = t >> 6, lane = t & 63;
    int l16 = lane & 15, quad = lane >> 4;
    int r0s = t >> 3, q4s = t & 7;            // A staging: rows 0..31 (p=0); rows 32..47 (p=1, t<128)

    f32x4 acc0[3][2], acc1[3][2], tot[3][2];
#pragma unroll
    for (int i = 0; i < 3; ++i)
#pragma unroll
        for (int j = 0; j < 2; ++j) {
            acc0[i][j] = f32x4{0.f, 0.f, 0.f, 0.f};
            acc1[i][j] = f32x4{0.f, 0.f, 0.f, 0.f};
            tot[i][j]  = f32x4{0.f, 0.f, 0.f, 0.f};
        }

    float4 ra[2];                             // A prefetch: 48x32 f32 = 384 f4 (1.5/thread)
    h8v rb[4];                                // B prefetch: 2 planes x 512 h8v, 4/thread

    // incremental chunk pointers: kn = k0 within relation, bump relation at 384
    const float* Ap = A0;
    const _Float16* Bhp = Bh0;
    const _Float16* Blp = Bl0;
    int kn = 0;

    // prologue: load chunk 0
#pragma unroll
    for (int p = 0; p < 2; ++p)
        if (p == 0 || t < 128)
            ra[p] = *(const float4*)(Ap + (size_t)(r0s + 32 * p) * 384 + kn + 4 * q4s);
#pragma unroll
    for (int p = 0; p < 4; ++p) {
        int si = t + 256 * (p & 1);
        int n = si >> 2, q8 = si & 3;
        const _Float16* Bsrc = (p < 2) ? Bhp : Blp;
        rb[p] = *(const h8v*)(Bsrc + (size_t)n * 384 + kn + 8 * q8);
    }
    kn += 32;

    for (int c = 0; c < 36; ++c) {
        // stage from regs into LDS (cvt for A; straight copy for B)
#pragma unroll
        for (int p = 0; p < 2; ++p) {
            if (p == 1 && t >= 128) break;
            int r = r0s + 32 * p;
            float vv[4] = {ra[p].x, ra[p].y, ra[p].z, ra[p].w};
            h4v hh, ll;
#pragma unroll
            for (int cc = 0; cc < 4; ++cc) {
                _Float16 h = (_Float16)vv[cc];
                hh[cc] = h;
                ll[cc] = (_Float16)((vv[cc] - (float)h) * SPLIT_SCALE);
            }
            *(h4v*)&Af[0][r >> 4][q4s >> 1][r & 15][(q4s & 1) * 4] = hh;
            *(h4v*)&Af[1][r >> 4][q4s >> 1][r & 15][(q4s & 1) * 4] = ll;
        }
#pragma unroll
        for (int p = 0; p < 4; ++p) {
            int si = t + 256 * (p & 1);
            int n = si >> 2, q8 = si & 3;
            *(h8v*)&Bf[p >> 1][n >> 4][q8][n & 15][0] = rb[p];
        }
        __syncthreads();
        if (c + 1 < 36) {                     // issue next chunk's loads (overlap with MFMA)
            if (kn == 384) {                  // advance to next relation e
                kn = 0;
                Ap += (size_t)ADJ_BE;
                Bhp += (size_t)128 * 384;
                Blp += (size_t)128 * 384;
            }
#pragma unroll
            for (int p = 0; p < 2; ++p)
                if (p == 0 || t < 128)
                    ra[p] = *(const float4*)(Ap + (size_t)(r0s + 32 * p) * 384 + kn + 4 * q4s);
#pragma unroll
            for (int p = 0; p < 4; ++p) {
                int si = t + 256 * (p & 1);
                int n = si >> 2, q8 = si & 3;
                const _Float16* Bsrc = (p < 2) ? Bhp : Blp;
                rb[p] = *(const h8v*)(Bsrc + (size_t)n * 384 + kn + 8 * q8);
            }
            kn += 32;
        }
        // A fragments (shared by all waves), B fragments for this wave's 32 cols
        h8v a_h[3], a_l[3];
#pragma unroll
        for (int i = 0; i < 3; ++i) {
            a_h[i] = *(const h8v*)&Af[0][i][quad][l16][0];
            a_l[i] = *(const h8v*)&Af[1][i][quad][l16][0];
        }
#pragma unroll
        for (int j = 0; j < 2; ++j) {
            h8v b_h = *(const h8v*)&Bf[0][2 * wave + j][quad][l16][0];
            h8v b_l = *(const h8v*)&Bf[1][2 * wave + j][quad][l16][0];
#pragma unroll
            for (int i = 0; i < 3; ++i) {
                acc0[i][j] = __builtin_amdgcn_mfma_f32_16x16x32_f16(a_h[i], b_h, acc0[i][j], 0, 0, 0);
                acc1[i][j] = __builtin_amdgcn_mfma_f32_16x16x32_f16(a_h[i], b_l, acc1[i][j], 0, 0, 0);
                acc1[i][j] = __builtin_amdgcn_mfma_f32_16x16x32_f16(a_l[i], b_h, acc1[i][j], 0, 0, 0);
            }
        }
        // relation boundary: fold with PER-E relu (reference: relu per e, then sum)
        if (c % 12 == 11) {
#pragma unroll
            for (int i = 0; i < 3; ++i)
#pragma unroll
                for (int j = 0; j < 2; ++j) {
#pragma unroll
                    for (int reg = 0; reg < 4; ++reg) {
                        float v = fmaf(acc1[i][j][reg], INV_SPLIT_SCALE, acc0[i][j][reg]);
                        if (RELU) v = fmaxf(v, 0.f);
                        tot[i][j][reg] += v;
                    }
                    acc0[i][j] = f32x4{0.f, 0.f, 0.f, 0.f};
                    acc1[i][j] = f32x4{0.f, 0.f, 0.f, 0.f};
                }
        }
        __syncthreads();
    }
    // epilogue: single plain store. C/D layout col=lane&15, row=quad*4+reg.
#pragma unroll
    for (int i = 0; i < 3; ++i) {
        int r0 = 16 * i + quad * 4;
#pragma unroll
        for (int j = 0; j < 2; ++j) {
            int gc = 32 * wave + 16 * j + l16;
#pragma unroll
            for (int reg = 0; reg < 4; ++reg)
                O[(size_t)(r0 + reg) * 128 + gc] = tot[i][j][reg];
        }
    }
}

// ---------------- kernel 5: fused head ----------------
__global__ __launch_bounds__(256) void k_head(const float* __restrict__ h3,
        const float* __restrict__ st_w1, const float* __restrict__ st_b1,
        const float* __restrict__ st_w2, const float* __restrict__ st_b2,
        const float* __restrict__ rescale_w, float* __restrict__ out) {
    __shared__ float hL[64][132];
    __shared__ float w1L[64][132];
    __shared__ float ytL[64][68];
    __shared__ float w2L[32][68];
    __shared__ float b1L[64], b2L[32];
    int t = threadIdx.x;
    int r0 = blockIdx.x * 64;
#pragma unroll
    for (int p = 0; p < 8; ++p) {   // h rows 64x128 = 2048 f4
        int idx = t + p * 256;
        int r = idx >> 5, q = idx & 31;
        *(float4*)&hL[r][q * 4] = *(const float4*)(h3 + (size_t)(r0 + r) * 128 + q * 4);
    }
#pragma unroll
    for (int p = 0; p < 8; ++p) {   // w1 64x128
        int idx = t + p * 256;
        int r = idx >> 5, q = idx & 31;
        *(float4*)&w1L[r][q * 4] = *(const float4*)(st_w1 + (size_t)r * 128 + q * 4);
    }
#pragma unroll
    for (int p = 0; p < 2; ++p) {   // w2 32x64 = 512 f4
        int idx = t + p * 256;
        int r = idx >> 4, q = idx & 15;
        *(float4*)&w2L[r][q * 4] = *(const float4*)(st_w2 + (size_t)r * 64 + q * 4);
    }
    if (t < 64) b1L[t] = st_b1[t];
    else if (t < 96) b2L[t - 64] = st_b2[t - 64];
    __syncthreads();
    // phase 1: y = h @ w1^T + b1, tanh
    int tx = t & 15, ty = t >> 4;
    float acc[4][4] = {};
    for (int d = 0; d < 128; ++d) {
        float a[4], w[4];
#pragma unroll
        for (int i = 0; i < 4; ++i) a[i] = hL[ty + 16 * i][d];
#pragma unroll
        for (int j = 0; j < 4; ++j) w[j] = w1L[tx + 16 * j][d];
#pragma unroll
        for (int i = 0; i < 4; ++i)
#pragma unroll
            for (int j = 0; j < 4; ++j)
                acc[i][j] = fmaf(a[i], w[j], acc[i][j]);
    }
#pragma unroll
    for (int i = 0; i < 4; ++i)
#pragma unroll
        for (int j = 0; j < 4; ++j)
            ytL[ty + 16 * i][tx + 16 * j] = tanhf(acc[i][j] + b1L[tx + 16 * j]);
    __syncthreads();
    // phase 2: z = yt @ w2^T + b2; split into s (tanh*exp(rescale)) and t
    int tx8 = t & 7, ty32 = t >> 3;
    float acc2[2][4] = {};
    for (int d = 0; d < 64; ++d) {
        float a[2], w[4];
#pragma unroll
        for (int i = 0; i < 2; ++i) a[i] = ytL[ty32 + 32 * i][d];
#pragma unroll
        for (int j = 0; j < 4; ++j) w[j] = w2L[tx8 + 8 * j][d];
#pragma unroll
        for (int i = 0; i < 2; ++i)
#pragma unroll
            for (int j = 0; j < 4; ++j)
                acc2[i][j] = fmaf(a[i], w[j], acc2[i][j]);
    }
    float er = expf(rescale_w[0]);
#pragma unroll
    for (int i = 0; i < 2; ++i) {
        int r = r0 + ty32 + 32 * i;
#pragma unroll
        for (int j = 0; j < 4; ++j) {
            int c = tx8 + 8 * j;
            float z = acc2[i][j] + b2L[c];
            if (c < 16) out[(size_t)r * 16 + c] = er * tanhf(z);
            else        out[(size_t)(ROWS + r) * 16 + (c - 16)] = z;
        }
    }
}

extern "C" void kernel_launch(void* const* d_in, const int* in_sizes, int n_in,
                              void* d_out, int out_size, void* d_ws, size_t ws_size,
                              hipStream_t stream) {
    const float* x     = (const float*)d_in[0];
    const float* adj   = (const float*)d_in[1];
    const float* emb_w = (const float*)d_in[2];
    const float* gc1   = (const float*)d_in[3];
    const float* gc2   = (const float*)d_in[4];
    const float* gc3   = (const float*)d_in[5];
    const float* st_w1 = (const float*)d_in[6];
    const float* st_b1 = (const float*)d_in[7];
    const float* st_w2 = (const float*)d_in[8];
    const float* st_b2 = (const float*)d_in[9];
    const float* resc  = (const float*)d_in[10];
    float* out = (float*)d_out;
    float* ws  = (float*)d_ws;

    // workspace layout: T1 4.7MB | hA 12.6MB | hB 12.6MB | Sh 18.9MB | Sl 18.9MB = 67.7MB
    float* T1 = ws;                          // 1179648 f
    float* hA = T1 + 1179648;                // 3145728 f (h1, later h3)
    float* hB = hA + 3145728;                // 3145728 f (h2)
    _Float16* Sh = (_Float16*)(hB + 3145728);  // 9437184 halves
    _Float16* Sl = Sh + 9437184;               // 9437184 halves
    // Hh/Hl (h0 split, 64*16*384 halves each = 1.5 MB total) live in the hB region,
    // which is dead until k_adj_fused<1> writes h2 (k_adj16 consumes them first).
    _Float16* Hh = (_Float16*)hB;
    _Float16* Hl = Hh + 393216;

    // layer 1 (reassociated): h0 = x@emb^T (split fp16), T = adj@h0 via MFMA, h1 = sum_e relu(T@W1)
    k_h0split<<<96, 256, 0, stream>>>(x, emb_w, Hh, Hl);
    k_adj16<<<dim3(6, 3, 64), 256, 0, stream>>>(adj, Hh, Hl, T1);
    k_l1s2<<<384, 256, 0, stream>>>(T1, gc1, hA);
    // layer 2 (e-fused adj pass: no zeroing, no atomics, per-e relu in-register)
    k_support<<<dim3(384, 3), 256, 0, stream>>>(hA, gc2, Sh, Sl);
    k_adj_fused<1><<<512, 256, 0, stream>>>(adj, Sh, Sl, hB);
    // layer 3 (no relu)
    k_support<<<dim3(384, 3), 256, 0, stream>>>(hB, gc3, Sh, Sl);
    k_adj_fused<0><<<512, 256, 0, stream>>>(adj, Sh, Sl, hA);
    // head
    k_head<<<384, 256, 0, stream>>>(hA, st_w1, st_b1, st_w2, st_b2, resc, out);
}